// Round 1
// 67.511 us; speedup vs baseline: 1.0520x; 1.0520x over previous
//
#include <hip/hip_runtime.h>

#define L 2048
#define B 16
#define TPB 256
#define BPR 64                  // blocks per batch row -> 1024 blocks, 4/CU
#define GAMMA 0.1f
#define EPT 8                   // elements per thread = L / TPB

// loss = (1/B) * sum_b [ sum_{a pos, j pos} relu((f_a-f_j)(x_a-x_j)) / (f_a+f_j)
//                      + GAMMA * sum_{a pos, j neg} relu(x_j - x_a) ]
//
// R4: (1) scan-based compaction: vectorized float4/int4 loads (all global
//     loads issued up-front), block-wide shfl prefix scan, NO LDS atomics,
//     2 barriers total. Replaces 8 serial {load,ballot,atomic,shfl} chains.
// (2) triangle-halved pos-pos loop: symmetric pairs computed once (j<a) and
//     doubled. a-list is stride-BPR interleaved (a = chunk + 64t) so triangle
//     area is balanced across chunks without sqrt partitioning. Invalid a's
//     are neutralized by value (pos: bound=0; neg: xa=1e30 -> term 0).
//     Halves pair-evals AND the quarter-rate v_rcp count.
// Keep two-kernel partials+reduce: R3 showed same-address atomicAdd fusion
// regresses +5us (cross-XCD serialization).
__global__ __launch_bounds__(TPB) void pair_loss_kernel(
    const float* __restrict__ input, const int* __restrict__ target,
    const float* __restrict__ freq, float* __restrict__ partial) {
  __shared__ float2 pf[L];            // 16 KB: compacted positives (x, f)
  __shared__ float nx[L];             // 8 KB: compacted negatives x
  __shared__ int wsum[TPB / 64];
  __shared__ float red[TPB / 64];

  const int b = blockIdx.x / BPR;
  const int chunk = blockIdx.x % BPR;
  const int tid = threadIdx.x;
  const int lane = tid & 63;
  const int wid = tid >> 6;

  // ---- vectorized load of this thread's 8 contiguous elements ----
  const float* row = input + b * L + tid * EPT;
  const int* trow = target + b * L + tid * EPT;
  const float* frow = freq + tid * EPT;

  const float4 xv0 = *(const float4*)(row);
  const float4 xv1 = *(const float4*)(row + 4);
  const int4 tv0 = *(const int4*)(trow);
  const int4 tv1 = *(const int4*)(trow + 4);
  const float4 fv0 = *(const float4*)(frow);
  const float4 fv1 = *(const float4*)(frow + 4);

  float x[EPT] = {xv0.x, xv0.y, xv0.z, xv0.w, xv1.x, xv1.y, xv1.z, xv1.w};
  float f[EPT] = {fv0.x, fv0.y, fv0.z, fv0.w, fv1.x, fv1.y, fv1.z, fv1.w};
  int tg[EPT] = {tv0.x, tv0.y, tv0.z, tv0.w, tv1.x, tv1.y, tv1.z, tv1.w};

  int myp = 0;
#pragma unroll
  for (int i = 0; i < EPT; ++i) {
    x[i] = 1.0f / (1.0f + __expf(-x[i]));
    myp += (tg[i] != 0) ? 1 : 0;
  }

  // ---- block-wide exclusive scan of positive counts (thread order ==
  //      element order since chunks are contiguous) ----
  int inc = myp;
#pragma unroll
  for (int off = 1; off < 64; off <<= 1) {
    int v = __shfl_up(inc, off, 64);
    if (lane >= off) inc += v;
  }
  if (lane == 63) wsum[wid] = inc;    // wave-inclusive totals
  __syncthreads();
  int wbase = 0, np = 0;
#pragma unroll
  for (int w = 0; w < TPB / 64; ++w) {
    int s = wsum[w];
    np += s;
    if (w < wid) wbase += s;
  }
  const int pbase0 = wbase + inc - myp;   // positives strictly before me
  int pi = pbase0;
  int ni = tid * EPT - pbase0;            // negatives strictly before me
#pragma unroll
  for (int i = 0; i < EPT; ++i) {
    if (tg[i] != 0) pf[pi++] = make_float2(x[i], f[i]);
    else           nx[ni++] = x[i];
  }
  __syncthreads();

  const int nn = L - np;

  float accp = 0.0f, accn = 0.0f;
  // a-list for this chunk: a = chunk + BPR*t (t = 0,1,2,...), grouped by 4.
  for (int A = chunk; A < np; A += 4 * BPR) {
    const int a0i = A, a1i = A + BPR, a2i = A + 2 * BPR, a3i = A + 3 * BPR;
    const bool v1 = a1i < np, v2 = a2i < np, v3 = a3i < np;
    const float2 af0 = pf[a0i];
    const float2 af1 = pf[v1 ? a1i : 0];
    const float2 af2 = pf[v2 ? a2i : 0];
    const float2 af3 = pf[v3 ? a3i : 0];
    const int b0 = a0i;                   // triangle bounds: j < b_i
    const int b1 = v1 ? a1i : 0;
    const int b2 = v2 ? a2i : 0;
    const int b3 = v3 ? a3i : 0;
    const int jend = v3 ? a3i : np;       // covers every valid bound

    for (int j = tid; j < jend; j += TPB) {
      float2 v = pf[j];                   // stride-1 ds_read_b64, shared by 4 a's
      float t0 = fmaxf((af0.y - v.y) * (af0.x - v.x), 0.0f) * __builtin_amdgcn_rcpf(af0.y + v.y);
      float t1 = fmaxf((af1.y - v.y) * (af1.x - v.x), 0.0f) * __builtin_amdgcn_rcpf(af1.y + v.y);
      float t2 = fmaxf((af2.y - v.y) * (af2.x - v.x), 0.0f) * __builtin_amdgcn_rcpf(af2.y + v.y);
      float t3 = fmaxf((af3.y - v.y) * (af3.x - v.x), 0.0f) * __builtin_amdgcn_rcpf(af3.y + v.y);
      accp += (j < b0) ? t0 : 0.0f;
      accp += (j < b1) ? t1 : 0.0f;
      accp += (j < b2) ? t2 : 0.0f;
      accp += (j < b3) ? t3 : 0.0f;
    }

    // pos-neg product is NOT symmetric: full nn loop per valid a.
    const float xa0 = af0.x;
    const float xa1 = v1 ? af1.x : 1e30f;  // xj - 1e30 < 0 -> relu 0
    const float xa2 = v2 ? af2.x : 1e30f;
    const float xa3 = v3 ? af3.x : 1e30f;
    for (int j = tid; j < nn; j += TPB) {
      float xj = nx[j];                   // stride-1 ds_read_b32
      accn += fmaxf(xj - xa0, 0.0f) + fmaxf(xj - xa1, 0.0f) +
              fmaxf(xj - xa2, 0.0f) + fmaxf(xj - xa3, 0.0f);
    }
  }
  // triangle counted once -> x2 (diagonal terms are exactly 0)
  float acc = 2.0f * accp + GAMMA * accn;

  // wave shuffle-reduce, then cross-wave via LDS
#pragma unroll
  for (int off = 32; off; off >>= 1) acc += __shfl_down(acc, off, 64);
  if (lane == 0) red[wid] = acc;
  __syncthreads();
  if (tid == 0) {
    float s = 0.0f;
#pragma unroll
    for (int w = 0; w < TPB / 64; ++w) s += red[w];
    partial[blockIdx.x] = s;
  }
}

__global__ __launch_bounds__(TPB) void reduce_kernel(
    const float* __restrict__ partial, float* __restrict__ out) {
  // exactly B*BPR = 1024 partials = 256 threads x float4
  float4 v = ((const float4*)partial)[threadIdx.x];
  float acc = (v.x + v.y) + (v.z + v.w);
#pragma unroll
  for (int off = 32; off; off >>= 1) acc += __shfl_down(acc, off, 64);
  __shared__ float red[TPB / 64];
  if ((threadIdx.x & 63) == 0) red[threadIdx.x >> 6] = acc;
  __syncthreads();
  if (threadIdx.x == 0) {
    float s = 0.0f;
#pragma unroll
    for (int w = 0; w < TPB / 64; ++w) s += red[w];
    out[0] = s * (1.0f / (float)B);
  }
}

extern "C" void kernel_launch(void* const* d_in, const int* in_sizes, int n_in,
                              void* d_out, int out_size, void* d_ws, size_t ws_size,
                              hipStream_t stream) {
  const float* input  = (const float*)d_in[0];   // [B, L] f32
  const int*   target = (const int*)d_in[1];     // [B, L] i32 (0/1)
  const float* freq   = (const float*)d_in[2];   // [L] f32, > 0
  float* out = (float*)d_out;                    // scalar f32
  float* partial = (float*)d_ws;                 // B*BPR floats of scratch

  const int nblocks = B * BPR;
  pair_loss_kernel<<<nblocks, TPB, 0, stream>>>(input, target, freq, partial);
  reduce_kernel<<<1, TPB, 0, stream>>>(partial, out);
}

// Round 2
// 66.477 us; speedup vs baseline: 1.0684x; 1.0156x over previous
//
#include <hip/hip_runtime.h>

#define L 2048
#define B 16
#define TPB 256
#define BPR 64                  // blocks per batch row -> 1024 blocks, 4/CU
#define GAMMA 0.1f
#define EPT 8                   // elements per thread = L / TPB

// loss = (1/B) * sum_b [ sum_{a pos, j pos} relu((f_a-f_j)(x_a-x_j)) / (f_a+f_j)
//                      + GAMMA * sum_{a pos, j neg} relu(x_j - x_a) ]
//
// R5: pos j-loop split into clean bulk + ragged epilogue.
//  - clean bulk (j < b0, even-aligned): ds_read_b128 loads 2 (x,f) pairs,
//    8 unpredicated evals of 6 VALU + 1 rcp each (fmaf accumulate). Invalid
//    a's value-neutralized (x=-1e19, f=+1e19 -> product<0 -> relu=0) so no
//    validity predicates needed in the bulk.
//  - ragged epilogue [b0e, bmax): ~0.75 iter/thread, per-a j<b_i predicates.
//  - neg loop float4 (1 iter/group for nn=1024) + scalar tail.
// Keeps R4 scan-based compaction (vectorized loads, shfl prefix scan, no LDS
// atomics) and the two-kernel partials+reduce (R3: atomic fusion regresses).
__global__ __launch_bounds__(TPB) void pair_loss_kernel(
    const float* __restrict__ input, const int* __restrict__ target,
    const float* __restrict__ freq, float* __restrict__ partial) {
  __shared__ float2 pf[L];            // 16 KB: compacted positives (x, f)
  __shared__ float nx[L];             // 8 KB: compacted negatives x
  __shared__ int wsum[TPB / 64];
  __shared__ float red[TPB / 64];

  const int b = blockIdx.x / BPR;
  const int chunk = blockIdx.x % BPR;
  const int tid = threadIdx.x;
  const int lane = tid & 63;
  const int wid = tid >> 6;

  // ---- vectorized load of this thread's 8 contiguous elements ----
  const float* row = input + b * L + tid * EPT;
  const int* trow = target + b * L + tid * EPT;
  const float* frow = freq + tid * EPT;

  const float4 xv0 = *(const float4*)(row);
  const float4 xv1 = *(const float4*)(row + 4);
  const int4 tv0 = *(const int4*)(trow);
  const int4 tv1 = *(const int4*)(trow + 4);
  const float4 fv0 = *(const float4*)(frow);
  const float4 fv1 = *(const float4*)(frow + 4);

  float x[EPT] = {xv0.x, xv0.y, xv0.z, xv0.w, xv1.x, xv1.y, xv1.z, xv1.w};
  float f[EPT] = {fv0.x, fv0.y, fv0.z, fv0.w, fv1.x, fv1.y, fv1.z, fv1.w};
  int tg[EPT] = {tv0.x, tv0.y, tv0.z, tv0.w, tv1.x, tv1.y, tv1.z, tv1.w};

  int myp = 0;
#pragma unroll
  for (int i = 0; i < EPT; ++i) {
    x[i] = 1.0f / (1.0f + __expf(-x[i]));
    myp += (tg[i] != 0) ? 1 : 0;
  }

  // ---- block-wide exclusive scan of positive counts ----
  int inc = myp;
#pragma unroll
  for (int off = 1; off < 64; off <<= 1) {
    int v = __shfl_up(inc, off, 64);
    if (lane >= off) inc += v;
  }
  if (lane == 63) wsum[wid] = inc;    // wave-inclusive totals
  __syncthreads();
  int wbase = 0, np = 0;
#pragma unroll
  for (int w = 0; w < TPB / 64; ++w) {
    int s = wsum[w];
    np += s;
    if (w < wid) wbase += s;
  }
  const int pbase0 = wbase + inc - myp;   // positives strictly before me
  int pi = pbase0;
  int ni = tid * EPT - pbase0;            // negatives strictly before me
#pragma unroll
  for (int i = 0; i < EPT; ++i) {
    if (tg[i] != 0) pf[pi++] = make_float2(x[i], f[i]);
    else           nx[ni++] = x[i];
  }
  __syncthreads();

  const int nn = L - np;
  const int nn4 = nn >> 2;

  float accp = 0.0f, accn = 0.0f;
  // a-list for this chunk: a = chunk + BPR*t, grouped by 4 (triangle-balanced)
  for (int A = chunk; A < np; A += 4 * BPR) {
    const int a0i = A, a1i = A + BPR, a2i = A + 2 * BPR, a3i = A + 3 * BPR;
    const bool v1 = a1i < np, v2 = a2i < np, v3 = a3i < np;
    const float2 q0 = pf[a0i];
    const float2 q1 = pf[v1 ? a1i : 0];
    const float2 q2 = pf[v2 ? a2i : 0];
    const float2 q3 = pf[v3 ? a3i : 0];
    // pos-eval operands; invalid -> (x=-1e19, f=+1e19): (f-fj)>0, (x-xj)<0
    // -> product<0 -> relu 0, rcp finite. No predicate needed in bulk.
    const float xp0 = q0.x,               fp0 = q0.y;
    const float xp1 = v1 ? q1.x : -1e19f, fp1 = v1 ? q1.y : 1e19f;
    const float xp2 = v2 ? q2.x : -1e19f, fp2 = v2 ? q2.y : 1e19f;
    const float xp3 = v3 ? q3.x : -1e19f, fp3 = v3 ? q3.y : 1e19f;
    const int b0 = a0i;                 // triangle bounds: j < b_i
    const int b1 = v1 ? a1i : 0;
    const int b2 = v2 ? a2i : 0;
    const int b3 = v3 ? a3i : 0;
    const int bmax = v3 ? a3i : (v2 ? a2i : (v1 ? a1i : a0i));
    const int b0e = b0 & ~1;            // even floor for paired reads

    // ---- clean bulk: j in [0, b0e), 2 j's per iter, unpredicated fmac ----
    for (int jj = tid; 2 * jj < b0e; jj += TPB) {
      const float4 v = *(const float4*)(&pf[2 * jj]);  // (xj0,fj0,xj1,fj1)
      accp = fmaf(fmaxf((fp0 - v.y) * (xp0 - v.x), 0.0f), __builtin_amdgcn_rcpf(fp0 + v.y), accp);
      accp = fmaf(fmaxf((fp1 - v.y) * (xp1 - v.x), 0.0f), __builtin_amdgcn_rcpf(fp1 + v.y), accp);
      accp = fmaf(fmaxf((fp2 - v.y) * (xp2 - v.x), 0.0f), __builtin_amdgcn_rcpf(fp2 + v.y), accp);
      accp = fmaf(fmaxf((fp3 - v.y) * (xp3 - v.x), 0.0f), __builtin_amdgcn_rcpf(fp3 + v.y), accp);
      accp = fmaf(fmaxf((fp0 - v.w) * (xp0 - v.z), 0.0f), __builtin_amdgcn_rcpf(fp0 + v.w), accp);
      accp = fmaf(fmaxf((fp1 - v.w) * (xp1 - v.z), 0.0f), __builtin_amdgcn_rcpf(fp1 + v.w), accp);
      accp = fmaf(fmaxf((fp2 - v.w) * (xp2 - v.z), 0.0f), __builtin_amdgcn_rcpf(fp2 + v.w), accp);
      accp = fmaf(fmaxf((fp3 - v.w) * (xp3 - v.z), 0.0f), __builtin_amdgcn_rcpf(fp3 + v.w), accp);
    }

    // ---- ragged epilogue: j in [b0e, bmax), per-a predicates ----
    int j0 = tid;
    if (b0e > tid) j0 = tid + (((b0e - tid + TPB - 1) >> 8) << 8);
    for (int j = j0; j < bmax; j += TPB) {
      const float2 v = pf[j];
      float m0 = fmaxf((fp0 - v.y) * (xp0 - v.x), 0.0f);
      float m1 = fmaxf((fp1 - v.y) * (xp1 - v.x), 0.0f);
      float m2 = fmaxf((fp2 - v.y) * (xp2 - v.x), 0.0f);
      float m3 = fmaxf((fp3 - v.y) * (xp3 - v.x), 0.0f);
      m0 = (j < b0) ? m0 : 0.0f;
      m1 = (j < b1) ? m1 : 0.0f;
      m2 = (j < b2) ? m2 : 0.0f;
      m3 = (j < b3) ? m3 : 0.0f;
      accp = fmaf(m0, __builtin_amdgcn_rcpf(fp0 + v.y), accp);
      accp = fmaf(m1, __builtin_amdgcn_rcpf(fp1 + v.y), accp);
      accp = fmaf(m2, __builtin_amdgcn_rcpf(fp2 + v.y), accp);
      accp = fmaf(m3, __builtin_amdgcn_rcpf(fp3 + v.y), accp);
    }

    // ---- neg loop: float4 reads; invalid a -> xa=+1e19 -> relu 0 ----
    const float xn0 = q0.x;
    const float xn1 = v1 ? q1.x : 1e19f;
    const float xn2 = v2 ? q2.x : 1e19f;
    const float xn3 = v3 ? q3.x : 1e19f;
    for (int jj = tid; jj < nn4; jj += TPB) {
      const float4 v = ((const float4*)nx)[jj];
      accn += fmaxf(v.x - xn0, 0.0f) + fmaxf(v.x - xn1, 0.0f) +
              fmaxf(v.x - xn2, 0.0f) + fmaxf(v.x - xn3, 0.0f);
      accn += fmaxf(v.y - xn0, 0.0f) + fmaxf(v.y - xn1, 0.0f) +
              fmaxf(v.y - xn2, 0.0f) + fmaxf(v.y - xn3, 0.0f);
      accn += fmaxf(v.z - xn0, 0.0f) + fmaxf(v.z - xn1, 0.0f) +
              fmaxf(v.z - xn2, 0.0f) + fmaxf(v.z - xn3, 0.0f);
      accn += fmaxf(v.w - xn0, 0.0f) + fmaxf(v.w - xn1, 0.0f) +
              fmaxf(v.w - xn2, 0.0f) + fmaxf(v.w - xn3, 0.0f);
    }
    for (int j = (nn & ~3) + tid; j < nn; j += TPB) {   // tail (<=3 elems)
      const float xj = nx[j];
      accn += fmaxf(xj - xn0, 0.0f) + fmaxf(xj - xn1, 0.0f) +
              fmaxf(xj - xn2, 0.0f) + fmaxf(xj - xn3, 0.0f);
    }
  }
  // triangle counted once -> x2 (diagonal terms are exactly 0)
  float acc = 2.0f * accp + GAMMA * accn;

  // wave shuffle-reduce, then cross-wave via LDS
#pragma unroll
  for (int off = 32; off; off >>= 1) acc += __shfl_down(acc, off, 64);
  if (lane == 0) red[wid] = acc;
  __syncthreads();
  if (tid == 0) {
    float s = 0.0f;
#pragma unroll
    for (int w = 0; w < TPB / 64; ++w) s += red[w];
    partial[blockIdx.x] = s;
  }
}

__global__ __launch_bounds__(TPB) void reduce_kernel(
    const float* __restrict__ partial, float* __restrict__ out) {
  // exactly B*BPR = 1024 partials = 256 threads x float4
  float4 v = ((const float4*)partial)[threadIdx.x];
  float acc = (v.x + v.y) + (v.z + v.w);
#pragma unroll
  for (int off = 32; off; off >>= 1) acc += __shfl_down(acc, off, 64);
  __shared__ float red[TPB / 64];
  if ((threadIdx.x & 63) == 0) red[threadIdx.x >> 6] = acc;
  __syncthreads();
  if (threadIdx.x == 0) {
    float s = 0.0f;
#pragma unroll
    for (int w = 0; w < TPB / 64; ++w) s += red[w];
    out[0] = s * (1.0f / (float)B);
  }
}

extern "C" void kernel_launch(void* const* d_in, const int* in_sizes, int n_in,
                              void* d_out, int out_size, void* d_ws, size_t ws_size,
                              hipStream_t stream) {
  const float* input  = (const float*)d_in[0];   // [B, L] f32
  const int*   target = (const int*)d_in[1];     // [B, L] i32 (0/1)
  const float* freq   = (const float*)d_in[2];   // [L] f32, > 0
  float* out = (float*)d_out;                    // scalar f32
  float* partial = (float*)d_ws;                 // B*BPR floats of scratch

  const int nblocks = B * BPR;
  pair_loss_kernel<<<nblocks, TPB, 0, stream>>>(input, target, freq, partial);
  reduce_kernel<<<1, TPB, 0, stream>>>(partial, out);
}